// Round 1
// baseline (227.488 us; speedup 1.0000x reference)
//
#include <hip/hip_runtime.h>

// 16-qubit statevector, iSWAP(t) on qubits (3,7), qubit 0 = MSB.
// bit positions: qubit 3 -> bit 12, qubit 7 -> bit 8.
constexpr int DIM    = 1 << 16;    // 65536
constexpr int BATCH  = 256;        // f32 per row; 64 float4
constexpr int COLS   = BATCH / 4;  // 64 float4 columns per row
constexpr int BIT_HI = 1 << 12;    // qubit 3
constexpr int BIT_LO = 1 << 8;     // qubit 7
constexpr int MASK_BOTH = BIT_HI | BIT_LO;  // 0x1100

// Fused-quadrant decomposition: one thread handles one float4 column of all
// four rows {b12,b8} = {00,01,10,11} of a group. 16384 groups x 64 cols.
constexpr int NGROUP = DIM / 4;        // 16384
constexpr int GWORK  = NGROUP * COLS;  // 1,048,576 threads total

// Clang native vector type: __builtin_nontemporal_* requires a native
// vector, not HIP's float4 class.
typedef float v4f __attribute__((ext_vector_type(4)));

// Insert 14 low bits of b into positions {0..7, 9..11, 13..15}
// (leaves bits 8 and 12 zero).
__device__ __forceinline__ int expand14(int b) {
    return (b & 0x00FF) | ((b & 0x0700) << 1) | ((b & 0x3800) << 2);
}

__global__ __launch_bounds__(256) void iswap_kernel(
    const float* __restrict__ sr, const float* __restrict__ si,
    const float* __restrict__ tp, float* __restrict__ out)
{
    const int gid = blockIdx.x * blockDim.x + threadIdx.x;
    float* __restrict__ out_r = out;
    float* __restrict__ out_i = out + (size_t)DIM * BATCH;

    // Fast trig: t in [0, 2pi), absmax threshold 0.0156 -> __sinf/__cosf are
    // plenty accurate and avoid libm sincos's pointer-output path.
    const float tv = tp[0];
    const float s = __sinf(tv);
    const float c = __cosf(tv);

    const int col  = gid & (COLS - 1);
    const int p    = gid >> 6;                 // [0, NGROUP)
    const int base = expand14(p);              // b12 = b8 = 0
    // All offsets < 2^24 floats -> 32-bit arithmetic, saddr+voffset friendly.
    const int o00 = base * BATCH + col * 4;
    const int o01 = o00 + BIT_LO * BATCH;      // b8  = 1
    const int o10 = o00 + BIT_HI * BATCH;      // b12 = 1
    const int o11 = o00 + MASK_BOTH * BATCH;   // both = 1

    // Streaming data, zero reuse: nontemporal to avoid L2 churn.
    // Pair rows first so the MFMA-free compute can start at vmcnt(4).
    const v4f r01 = __builtin_nontemporal_load((const v4f*)(sr + o01));
    const v4f m01 = __builtin_nontemporal_load((const v4f*)(si + o01));
    const v4f r10 = __builtin_nontemporal_load((const v4f*)(sr + o10));
    const v4f m10 = __builtin_nontemporal_load((const v4f*)(si + o10));
    // Pass-through rows (b12 == b8): pure copy.
    const v4f r00 = __builtin_nontemporal_load((const v4f*)(sr + o00));
    const v4f m00 = __builtin_nontemporal_load((const v4f*)(si + o00));
    const v4f r11 = __builtin_nontemporal_load((const v4f*)(sr + o11));
    const v4f m11 = __builtin_nontemporal_load((const v4f*)(si + o11));

    // new01 = c*old01 - i*s*old10 ; new10 = c*old10 - i*s*old01
    // re(new01) = c*r01 + s*m10 ; im(new01) = c*m01 - s*r10  (sym. for 10)
    const v4f nr01 = c * r01 + s * m10;
    const v4f ni01 = c * m01 - s * r10;
    const v4f nr10 = c * r10 + s * m01;
    const v4f ni10 = c * m10 - s * r01;

    __builtin_nontemporal_store(nr01, (v4f*)(out_r + o01));
    __builtin_nontemporal_store(ni01, (v4f*)(out_i + o01));
    __builtin_nontemporal_store(nr10, (v4f*)(out_r + o10));
    __builtin_nontemporal_store(ni10, (v4f*)(out_i + o10));
    __builtin_nontemporal_store(r00,  (v4f*)(out_r + o00));
    __builtin_nontemporal_store(m00,  (v4f*)(out_i + o00));
    __builtin_nontemporal_store(r11,  (v4f*)(out_r + o11));
    __builtin_nontemporal_store(m11,  (v4f*)(out_i + o11));
}

extern "C" void kernel_launch(void* const* d_in, const int* in_sizes, int n_in,
                              void* d_out, int out_size, void* d_ws, size_t ws_size,
                              hipStream_t stream) {
    const float* sr = (const float*)d_in[0];
    const float* si = (const float*)d_in[1];
    const float* t  = (const float*)d_in[2];
    float* out = (float*)d_out;

    static_assert(GWORK % 256 == 0, "grid sizing");
    iswap_kernel<<<dim3(GWORK / 256), dim3(256), 0, stream>>>(sr, si, t, out);
}